// Round 1
// baseline (542.593 us; speedup 1.0000x reference)
//
#include <hip/hip_runtime.h>
#include <hip/hip_bf16.h>
#include <cstdint>
#include <cstddef>

#define TOK   8192
#define DIN   4096
#define DOUT  4096
#define RANK  16
#define KE    4128   // DIN + 16 (loraB) + 1 (bias col) + 15 pad  -> multiple of 32

#define BM 128
#define BN 128
#define BK 32
#define NT (DOUT / BN)   // 32 column tiles

typedef __attribute__((ext_vector_type(8))) short bf16x8;
typedef __attribute__((ext_vector_type(4))) float f32x4;
typedef __attribute__((ext_vector_type(8))) unsigned short u16x8;

__device__ __constant__ float NF4_CODE_D[16] = {
    -1.0f, -0.6961928009986877f, -0.5250730514526367f, -0.39491748809814453f,
    -0.28444138169288635f, -0.18477343022823334f, -0.09105003625154495f, 0.0f,
    0.07958029955625534f, 0.16093020141124725f, 0.24611230194568634f,
    0.33791524171829224f, 0.44070982933044434f, 0.5626170039176941f,
    0.7229568362236023f, 1.0f};

__device__ __forceinline__ unsigned short f2bf(float f) {
    union { float f; unsigned u; } v; v.f = f;
    unsigned u = v.u;
    unsigned r = (u + 0x7FFFu + ((u >> 16) & 1u)) >> 16;  // round-nearest-even
    return (unsigned short)r;
}

__device__ __forceinline__ void async_copy16(const void* g, void* l) {
    __builtin_amdgcn_global_load_lds(
        (const __attribute__((address_space(1))) void*)g,
        (__attribute__((address_space(3))) void*)l,
        16, 0, 0);
}

// ---------------------------------------------------------------------------
// Kernel 1: convert x -> bf16 into extended layout [TOK][KE], and compute
// t = SCALING * (x @ lora_A) into cols [4096,4112); col 4112 = 1.0 (bias col);
// cols [4113,4128) = 0.
// Block = 256 thr = 4 waves; wave handles 4 tokens; lane covers k = it*256+l*4+j.
// ---------------------------------------------------------------------------
__global__ __launch_bounds__(256) void prep_x(const float* __restrict__ x,
                                              const float* __restrict__ lora_A,
                                              unsigned short* __restrict__ xe) {
    const int tid = threadIdx.x;
    const int l = tid & 63;
    const int w = tid >> 6;
    const int t0 = blockIdx.x * 16 + w * 4;

    float p[4][16];
#pragma unroll
    for (int a = 0; a < 4; ++a)
#pragma unroll
        for (int r = 0; r < 16; ++r) p[a][r] = 0.f;

    for (int it = 0; it < 16; ++it) {
        const int kb = it * 256 + l * 4;
        float4 xv[4];
#pragma unroll
        for (int a = 0; a < 4; ++a)
            xv[a] = *(const float4*)(x + (size_t)(t0 + a) * DIN + kb);
#pragma unroll
        for (int a = 0; a < 4; ++a) {
            ushort4 s;
            s.x = f2bf(xv[a].x); s.y = f2bf(xv[a].y);
            s.z = f2bf(xv[a].z); s.w = f2bf(xv[a].w);
            *(ushort4*)(xe + (size_t)(t0 + a) * KE + kb) = s;
        }
#pragma unroll
        for (int j = 0; j < 4; ++j) {
            const float4* ap = (const float4*)(lora_A + (size_t)(kb + j) * RANK);
            const float4 a0 = ap[0], a1 = ap[1], a2 = ap[2], a3 = ap[3];
            const float av[16] = {a0.x, a0.y, a0.z, a0.w, a1.x, a1.y, a1.z, a1.w,
                                  a2.x, a2.y, a2.z, a2.w, a3.x, a3.y, a3.z, a3.w};
#pragma unroll
            for (int a = 0; a < 4; ++a) {
                const float xs = (j == 0) ? xv[a].x : (j == 1) ? xv[a].y
                                : (j == 2) ? xv[a].z : xv[a].w;
#pragma unroll
                for (int r = 0; r < 16; ++r) p[a][r] += xs * av[r];
            }
        }
    }

    // wave reduction and tail write
#pragma unroll
    for (int a = 0; a < 4; ++a) {
#pragma unroll
        for (int r = 0; r < 16; ++r) {
            float v = p[a][r];
#pragma unroll
            for (int off = 32; off > 0; off >>= 1) v += __shfl_xor(v, off, 64);
            if (l == r)
                xe[(size_t)(t0 + a) * KE + DIN + r] = f2bf(4.0f * v);  // SCALING=4
        }
        if (l >= 16 && l < 32)
            xe[(size_t)(t0 + a) * KE + DIN + l] =
                (l == 16) ? (unsigned short)0x3F80u : (unsigned short)0u;
    }
}

// ---------------------------------------------------------------------------
// Kernel 2: NF4 dequant W -> bf16 into [DOUT][KE], cols [0,4096).
// Thread handles 8 codes (all in one absmax block since 8 | 64).
// ---------------------------------------------------------------------------
__global__ __launch_bounds__(256) void dequant_w(const int* __restrict__ codes,
                                                 const float* __restrict__ absmax,
                                                 unsigned short* __restrict__ we) {
    __shared__ float tab[16];
    if (threadIdx.x < 16) tab[threadIdx.x] = NF4_CODE_D[threadIdx.x];
    __syncthreads();
    const size_t tid = (size_t)blockIdx.x * 256 + threadIdx.x;
    const size_t base = tid * 8;
    const int o = (int)(base >> 12);          // / DIN
    const int k = (int)(base & (DIN - 1));
    const float am = absmax[base >> 6];
    const int4 c0 = *(const int4*)(codes + base);
    const int4 c1 = *(const int4*)(codes + base + 4);
    u16x8 ov;
    ov[0] = f2bf(tab[c0.x] * am);
    ov[1] = f2bf(tab[c0.y] * am);
    ov[2] = f2bf(tab[c0.z] * am);
    ov[3] = f2bf(tab[c0.w] * am);
    ov[4] = f2bf(tab[c1.x] * am);
    ov[5] = f2bf(tab[c1.y] * am);
    ov[6] = f2bf(tab[c1.z] * am);
    ov[7] = f2bf(tab[c1.w] * am);
    *(u16x8*)(we + (size_t)o * KE + k) = ov;
}

// ---------------------------------------------------------------------------
// Kernel 3: fill W extended tail: cols [4096,4112) = lora_B^T, 4112 = bias,
// [4113,4128) = 0.
// ---------------------------------------------------------------------------
__global__ __launch_bounds__(256) void fill_wtail(const float* __restrict__ lora_B,
                                                  const float* __restrict__ bias,
                                                  unsigned short* __restrict__ we) {
    const int o = blockIdx.x * 256 + threadIdx.x;
    if (o >= DOUT) return;
    unsigned short* dst = we + (size_t)o * KE + DIN;
#pragma unroll
    for (int r = 0; r < RANK; ++r) dst[r] = f2bf(lora_B[(size_t)r * DOUT + o]);
    dst[16] = f2bf(bias[o]);
#pragma unroll
    for (int r = 17; r < 32; ++r) dst[r] = 0;
}

// ---------------------------------------------------------------------------
// Kernel 4: C[t,o] = sum_k A[t,k]*B[o,k]   (both K-major bf16, K=KE=4128)
// m97 structure: 128x128 tile, BK=32, 4 waves (2x2), 16x16x32 MFMA,
// global_load_lds width 16, store-only epilogue (bias+lora already in K).
// ---------------------------------------------------------------------------
__global__ __launch_bounds__(256) void gemm_bt(const unsigned short* __restrict__ A,
                                               const unsigned short* __restrict__ B,
                                               float* __restrict__ C) {
    __shared__ __align__(16) unsigned short As[BM * BK];
    __shared__ __align__(16) unsigned short Bs[BM * BK];

    const int tid = threadIdx.x;
    const int l = tid & 63;
    const int w = tid >> 6;
    const int wm = w >> 1, wn = w & 1;

    const int tm = blockIdx.x / NT;
    const int tn = blockIdx.x % NT;
    const int rowBase = tm * BM;
    const int colBase = tn * BN;

    // staging: per wave-issue, LDS = uniform base + lane*16B (linear layout)
    const int srow = w * 16 + (l >> 2);     // row within 64-row half-tile
    const int scol = (l & 3) * 8;           // bf16 col offset
    const unsigned short* Ag = A + (size_t)(rowBase + srow) * KE + scol;
    const unsigned short* Bg = B + (size_t)(colBase + srow) * KE + scol;
    char* AsL = (char*)As + w * 1024;
    char* BsL = (char*)Bs + w * 1024;

    f32x4 acc[4][4];
#pragma unroll
    for (int m = 0; m < 4; ++m)
#pragma unroll
        for (int n = 0; n < 4; ++n) acc[m][n] = (f32x4){0.f, 0.f, 0.f, 0.f};

    const int lr = l & 15;
    const int lk = (l >> 4) * 8;

    for (int k0 = 0; k0 < KE; k0 += BK) {
        __syncthreads();
#pragma unroll
        for (int j = 0; j < 2; ++j) {
            async_copy16(Ag + (size_t)(j * 64) * KE + k0, AsL + j * 4096);
            async_copy16(Bg + (size_t)(j * 64) * KE + k0, BsL + j * 4096);
        }
        __syncthreads();

        bf16x8 af[4], bv[4];
#pragma unroll
        for (int m = 0; m < 4; ++m)
            af[m] = *(const bf16x8*)(As + (wm * 64 + m * 16 + lr) * BK + lk);
#pragma unroll
        for (int n = 0; n < 4; ++n)
            bv[n] = *(const bf16x8*)(Bs + (wn * 64 + n * 16 + lr) * BK + lk);
#pragma unroll
        for (int m = 0; m < 4; ++m)
#pragma unroll
            for (int n = 0; n < 4; ++n)
                acc[m][n] = __builtin_amdgcn_mfma_f32_16x16x32_bf16(
                    af[m], bv[n], acc[m][n], 0, 0, 0);
    }

    // epilogue: pure store. C/D map: col = l&15, row = (l>>4)*4 + reg
#pragma unroll
    for (int m = 0; m < 4; ++m) {
        const int rowg = rowBase + wm * 64 + m * 16 + (l >> 4) * 4;
#pragma unroll
        for (int n = 0; n < 4; ++n) {
            const int colg = colBase + wn * 64 + n * 16 + lr;
            float* cp = C + (size_t)rowg * DOUT + colg;
#pragma unroll
            for (int r = 0; r < 4; ++r) cp[(size_t)r * DOUT] = acc[m][n][r];
        }
    }
}

// ---------------------------------------------------------------------------
extern "C" void kernel_launch(void* const* d_in, const int* in_sizes, int n_in,
                              void* d_out, int out_size, void* d_ws, size_t ws_size,
                              hipStream_t stream) {
    const float* x      = (const float*)d_in[0];
    const int*   codes  = (const int*)d_in[1];
    const float* absmax = (const float*)d_in[2];
    const float* bias   = (const float*)d_in[3];
    const float* lora_A = (const float*)d_in[4];
    const float* lora_B = (const float*)d_in[5];
    float* out = (float*)d_out;

    unsigned short* xe = (unsigned short*)d_ws;        // [TOK][KE] bf16
    unsigned short* we = xe + (size_t)TOK * KE;        // [DOUT][KE] bf16

    prep_x<<<TOK / 16, 256, 0, stream>>>(x, lora_A, xe);
    dequant_w<<<(DOUT * (size_t)DIN / 8) / 256, 256, 0, stream>>>(codes, absmax, we);
    fill_wtail<<<DOUT / 256, 256, 0, stream>>>(lora_B, bias, we);
    gemm_bt<<<(TOK / BM) * (DOUT / BN), 256, 0, stream>>>(xe, we, out);
}

// Round 2
// 375.496 us; speedup vs baseline: 1.4450x; 1.4450x over previous
//
#include <hip/hip_runtime.h>
#include <hip/hip_bf16.h>
#include <cstdint>
#include <cstddef>

#define TOK   8192
#define DIN   4096
#define DOUT  4096
#define RANK  16
#define KE    4128   // DIN + 16 (loraB) + 1 (bias col) + 15 pad  -> multiple of 32

#define BM 256
#define BN 256
#define BKT 32               // K depth per LDS tile
#define NKT (KE / BKT)       // 129 K-tiles
#define NBUF 3               // triple buffer -> counted vmcnt, depth-2 prefetch

typedef __attribute__((ext_vector_type(8))) short bf16x8;
typedef __attribute__((ext_vector_type(4))) float f32x4;
typedef __attribute__((ext_vector_type(8))) unsigned short u16x8;

__device__ __constant__ float NF4_CODE_D[16] = {
    -1.0f, -0.6961928009986877f, -0.5250730514526367f, -0.39491748809814453f,
    -0.28444138169288635f, -0.18477343022823334f, -0.09105003625154495f, 0.0f,
    0.07958029955625534f, 0.16093020141124725f, 0.24611230194568634f,
    0.33791524171829224f, 0.44070982933044434f, 0.5626170039176941f,
    0.7229568362236023f, 1.0f};

__device__ __forceinline__ unsigned short f2bf(float f) {
    union { float f; unsigned u; } v; v.f = f;
    unsigned u = v.u;
    unsigned r = (u + 0x7FFFu + ((u >> 16) & 1u)) >> 16;  // round-nearest-even
    return (unsigned short)r;
}

__device__ __forceinline__ void async_copy16(const void* g, void* l) {
    __builtin_amdgcn_global_load_lds(
        (const __attribute__((address_space(1))) void*)g,
        (__attribute__((address_space(3))) void*)l,
        16, 0, 0);
}

// ---------------------------------------------------------------------------
// Kernel 1: x -> bf16 into [TOK][KE]; cols [4096,4112) = 4*(x@lora_A);
// col 4112 = 1.0 (bias col); [4113,4128) = 0.
// ---------------------------------------------------------------------------
__global__ __launch_bounds__(256) void prep_x(const float* __restrict__ x,
                                              const float* __restrict__ lora_A,
                                              unsigned short* __restrict__ xe) {
    const int tid = threadIdx.x;
    const int l = tid & 63;
    const int w = tid >> 6;
    const int t0 = blockIdx.x * 16 + w * 4;

    float p[4][16];
#pragma unroll
    for (int a = 0; a < 4; ++a)
#pragma unroll
        for (int r = 0; r < 16; ++r) p[a][r] = 0.f;

    for (int it = 0; it < 16; ++it) {
        const int kb = it * 256 + l * 4;
        float4 xv[4];
#pragma unroll
        for (int a = 0; a < 4; ++a)
            xv[a] = *(const float4*)(x + (size_t)(t0 + a) * DIN + kb);
#pragma unroll
        for (int a = 0; a < 4; ++a) {
            ushort4 s;
            s.x = f2bf(xv[a].x); s.y = f2bf(xv[a].y);
            s.z = f2bf(xv[a].z); s.w = f2bf(xv[a].w);
            *(ushort4*)(xe + (size_t)(t0 + a) * KE + kb) = s;
        }
#pragma unroll
        for (int j = 0; j < 4; ++j) {
            const float4* ap = (const float4*)(lora_A + (size_t)(kb + j) * RANK);
            const float4 a0 = ap[0], a1 = ap[1], a2 = ap[2], a3 = ap[3];
            const float av[16] = {a0.x, a0.y, a0.z, a0.w, a1.x, a1.y, a1.z, a1.w,
                                  a2.x, a2.y, a2.z, a2.w, a3.x, a3.y, a3.z, a3.w};
#pragma unroll
            for (int a = 0; a < 4; ++a) {
                const float xs = (j == 0) ? xv[a].x : (j == 1) ? xv[a].y
                                : (j == 2) ? xv[a].z : xv[a].w;
#pragma unroll
                for (int r = 0; r < 16; ++r) p[a][r] += xs * av[r];
            }
        }
    }

#pragma unroll
    for (int a = 0; a < 4; ++a) {
#pragma unroll
        for (int r = 0; r < 16; ++r) {
            float v = p[a][r];
#pragma unroll
            for (int off = 32; off > 0; off >>= 1) v += __shfl_xor(v, off, 64);
            if (l == r)
                xe[(size_t)(t0 + a) * KE + DIN + r] = f2bf(4.0f * v);  // SCALING=4
        }
        if (l >= 16 && l < 32)
            xe[(size_t)(t0 + a) * KE + DIN + l] =
                (l == 16) ? (unsigned short)0x3F80u : (unsigned short)0u;
    }
}

// ---------------------------------------------------------------------------
// Kernel 2: NF4 dequant W -> bf16 into [DOUT][KE], cols [0,4096).
// ---------------------------------------------------------------------------
__global__ __launch_bounds__(256) void dequant_w(const int* __restrict__ codes,
                                                 const float* __restrict__ absmax,
                                                 unsigned short* __restrict__ we) {
    __shared__ float tab[16];
    if (threadIdx.x < 16) tab[threadIdx.x] = NF4_CODE_D[threadIdx.x];
    __syncthreads();
    const size_t tid = (size_t)blockIdx.x * 256 + threadIdx.x;
    const size_t base = tid * 8;
    const int o = (int)(base >> 12);          // / DIN
    const int k = (int)(base & (DIN - 1));
    const float am = absmax[base >> 6];
    const int4 c0 = *(const int4*)(codes + base);
    const int4 c1 = *(const int4*)(codes + base + 4);
    u16x8 ov;
    ov[0] = f2bf(tab[c0.x] * am);
    ov[1] = f2bf(tab[c0.y] * am);
    ov[2] = f2bf(tab[c0.z] * am);
    ov[3] = f2bf(tab[c0.w] * am);
    ov[4] = f2bf(tab[c1.x] * am);
    ov[5] = f2bf(tab[c1.y] * am);
    ov[6] = f2bf(tab[c1.z] * am);
    ov[7] = f2bf(tab[c1.w] * am);
    *(u16x8*)(we + (size_t)o * KE + k) = ov;
}

// ---------------------------------------------------------------------------
// Kernel 3: W extended tail: cols [4096,4112) = lora_B^T, 4112 = bias, rest 0.
// ---------------------------------------------------------------------------
__global__ __launch_bounds__(256) void fill_wtail(const float* __restrict__ lora_B,
                                                  const float* __restrict__ bias,
                                                  unsigned short* __restrict__ we) {
    const int o = blockIdx.x * 256 + threadIdx.x;
    if (o >= DOUT) return;
    unsigned short* dst = we + (size_t)o * KE + DIN;
#pragma unroll
    for (int r = 0; r < RANK; ++r) dst[r] = f2bf(lora_B[(size_t)r * DOUT + o]);
    dst[16] = f2bf(bias[o]);
#pragma unroll
    for (int r = 17; r < 32; ++r) dst[r] = 0;
}

// ---------------------------------------------------------------------------
// Kernel 4: C[t,o] = sum_k A[t,k]*B[o,k]  (K-major bf16, K=KE)
// R2 structure: 256x256 tile, BK=32, 8 waves (2x4), TRIPLE-buffered LDS,
// counted s_waitcnt vmcnt(4) (never 0 in main loop), one raw s_barrier per
// K-tile, bank-conflict-free XOR swizzle (bits[9:7] -> bits[6:4], involution,
// applied to pre-swizzled global source + read offsets; LDS dest stays linear
// as global_load_lds requires).
//
// Ledger (per-wave, 4 loads/tile): at iter t's wait, outstanding = stages
// t (maybe) + t+1 (newest 4) -> vmcnt(4) retires tile t. stage(t+2) is issued
// AFTER BAR(t) into tile (t-1)'s buffer, whose readers all finished before
// reaching BAR(t) -> WAR-safe with a single barrier per tile.
// ---------------------------------------------------------------------------
__global__ __launch_bounds__(512, 2) void gemm_bt(const unsigned short* __restrict__ A,
                                                  const unsigned short* __restrict__ B,
                                                  float* __restrict__ C) {
    __shared__ __attribute__((aligned(1024))) char smem[NBUF * 32768];  // 96 KiB

    const int tid = threadIdx.x;
    const int l = tid & 63;
    const int w = tid >> 6;
    const int wm = w >> 2;      // 0..1
    const int wn = w & 3;       // 0..3

    const int tm = blockIdx.x >> 4;     // 32 row tiles
    const int tn = blockIdx.x & 15;     // 16 col tiles
    const int rowBase = tm * BM;
    const int colBase = tn * BN;

    // staging source coords (pre-swizzled so linear LDS + swizzled read match)
    int srow[2], scolb[2], loffs[2];
#pragma unroll
    for (int g = 0; g < 2; ++g) {
        const int loff = g * 8192 + tid * 16;            // linear LDS byte off
        const int soff = loff ^ (((loff >> 7) & 7) << 4);  // involution
        loffs[g] = loff;
        srow[g] = soff >> 6;          // row (64B rows, [256][32] bf16 tile)
        scolb[g] = soff & 63;         // byte within row
    }

    auto stage = [&](int t) {
        char* Ad = smem + (t % NBUF) * 32768;
        char* Bd = Ad + 16384;
        const int k0 = t * BKT;
#pragma unroll
        for (int g = 0; g < 2; ++g)
            async_copy16((const char*)A + ((size_t)(rowBase + srow[g]) * KE + k0) * 2 + scolb[g],
                         Ad + loffs[g]);
#pragma unroll
        for (int g = 0; g < 2; ++g)
            async_copy16((const char*)B + ((size_t)(colBase + srow[g]) * KE + k0) * 2 + scolb[g],
                         Bd + loffs[g]);
    };

    // swizzled read offsets: logical = row*64 + (l>>4)*16; XOR mask depends
    // only on lane bits (row bits 1..3 == lane bits 1..3)
    const int lmask = ((l >> 1) & 7) << 4;
    const int aoff = (((wm * 128 + (l & 15)) * 64) + ((l >> 4) * 16)) ^ lmask;
    const int boff = (((wn * 64 + (l & 15)) * 64) + ((l >> 4) * 16)) ^ lmask;

    f32x4 acc[8][4];
#pragma unroll
    for (int m = 0; m < 8; ++m)
#pragma unroll
        for (int n = 0; n < 4; ++n) acc[m][n] = (f32x4){0.f, 0.f, 0.f, 0.f};

    stage(0);
    stage(1);

    for (int t = 0; t < NKT; ++t) {
        if (t < NKT - 1) {
            asm volatile("s_waitcnt vmcnt(4)" ::: "memory");
        } else {
            asm volatile("s_waitcnt vmcnt(0)" ::: "memory");
        }
        __builtin_amdgcn_s_barrier();
        __builtin_amdgcn_sched_barrier(0);

        if (t + 2 < NKT) stage(t + 2);

        const char* At = smem + (t % NBUF) * 32768;
        const char* Bt = At + 16384;

        bf16x8 bfr[4];
#pragma unroll
        for (int n = 0; n < 4; ++n)
            bfr[n] = *(const bf16x8*)(Bt + boff + n * 1024);
#pragma unroll
        for (int m = 0; m < 8; ++m) {
            const bf16x8 af = *(const bf16x8*)(At + aoff + m * 1024);
#pragma unroll
            for (int n = 0; n < 4; ++n)
                acc[m][n] = __builtin_amdgcn_mfma_f32_16x16x32_bf16(
                    af, bfr[n], acc[m][n], 0, 0, 0);
        }
    }

    // epilogue: C/D map col = l&15, row = (l>>4)*4 + reg
#pragma unroll
    for (int m = 0; m < 8; ++m) {
        const int rowg = rowBase + wm * 128 + m * 16 + (l >> 4) * 4;
#pragma unroll
        for (int n = 0; n < 4; ++n) {
            const int colg = colBase + wn * 64 + n * 16 + (l & 15);
            float* cp = C + (size_t)rowg * DOUT + colg;
#pragma unroll
            for (int r = 0; r < 4; ++r) cp[(size_t)r * DOUT] = acc[m][n][r];
        }
    }
}

// ---------------------------------------------------------------------------
extern "C" void kernel_launch(void* const* d_in, const int* in_sizes, int n_in,
                              void* d_out, int out_size, void* d_ws, size_t ws_size,
                              hipStream_t stream) {
    const float* x      = (const float*)d_in[0];
    const int*   codes  = (const int*)d_in[1];
    const float* absmax = (const float*)d_in[2];
    const float* bias   = (const float*)d_in[3];
    const float* lora_A = (const float*)d_in[4];
    const float* lora_B = (const float*)d_in[5];
    float* out = (float*)d_out;

    unsigned short* xe = (unsigned short*)d_ws;        // [TOK][KE] bf16
    unsigned short* we = xe + (size_t)TOK * KE;        // [DOUT][KE] bf16

    prep_x<<<TOK / 16, 256, 0, stream>>>(x, lora_A, xe);
    dequant_w<<<(DOUT * (size_t)DIN / 8) / 256, 256, 0, stream>>>(codes, absmax, we);
    fill_wtail<<<DOUT / 256, 256, 0, stream>>>(lora_B, bias, we);
    gemm_bt<<<(TOK / BM) * (DOUT / BN), 512, 0, stream>>>(xe, we, out);
}

// Round 3
// 370.131 us; speedup vs baseline: 1.4659x; 1.0145x over previous
//
#include <hip/hip_runtime.h>
#include <hip/hip_bf16.h>
#include <cstdint>
#include <cstddef>

#define TOK   8192
#define DIN   4096
#define DOUT  4096
#define RANK  16
#define KE    4160   // DIN + 16 (loraB) + 1 (bias) + 47 pad -> 65 * 64
#define NKT64 (KE / 64)

#define BM 256
#define BN 256

typedef __attribute__((ext_vector_type(8))) short bf16x8;
typedef __attribute__((ext_vector_type(4))) float f32x4;
typedef __attribute__((ext_vector_type(8))) unsigned short u16x8;

__device__ __constant__ float NF4_CODE_D[16] = {
    -1.0f, -0.6961928009986877f, -0.5250730514526367f, -0.39491748809814453f,
    -0.28444138169288635f, -0.18477343022823334f, -0.09105003625154495f, 0.0f,
    0.07958029955625534f, 0.16093020141124725f, 0.24611230194568634f,
    0.33791524171829224f, 0.44070982933044434f, 0.5626170039176941f,
    0.7229568362236023f, 1.0f};

__device__ __forceinline__ unsigned short f2bf(float f) {
    union { float f; unsigned u; } v; v.f = f;
    unsigned u = v.u;
    unsigned r = (u + 0x7FFFu + ((u >> 16) & 1u)) >> 16;  // round-nearest-even
    return (unsigned short)r;
}

__device__ __forceinline__ void async_copy16(const void* g, void* l) {
    __builtin_amdgcn_global_load_lds(
        (const __attribute__((address_space(1))) void*)g,
        (__attribute__((address_space(3))) void*)l,
        16, 0, 0);
}

// ---------------------------------------------------------------------------
// Kernel 1: x -> bf16 into [TOK][KE]; cols [4096,4112) = 4*(x@lora_A);
// col 4112 = 1.0 (bias col); [4113,4160) = 0.
// ---------------------------------------------------------------------------
__global__ __launch_bounds__(256) void prep_x(const float* __restrict__ x,
                                              const float* __restrict__ lora_A,
                                              unsigned short* __restrict__ xe) {
    const int tid = threadIdx.x;
    const int l = tid & 63;
    const int w = tid >> 6;
    const int t0 = blockIdx.x * 16 + w * 4;

    float p[4][16];
#pragma unroll
    for (int a = 0; a < 4; ++a)
#pragma unroll
        for (int r = 0; r < 16; ++r) p[a][r] = 0.f;

    for (int it = 0; it < 16; ++it) {
        const int kb = it * 256 + l * 4;
        float4 xv[4];
#pragma unroll
        for (int a = 0; a < 4; ++a)
            xv[a] = *(const float4*)(x + (size_t)(t0 + a) * DIN + kb);
#pragma unroll
        for (int a = 0; a < 4; ++a) {
            ushort4 s;
            s.x = f2bf(xv[a].x); s.y = f2bf(xv[a].y);
            s.z = f2bf(xv[a].z); s.w = f2bf(xv[a].w);
            *(ushort4*)(xe + (size_t)(t0 + a) * KE + kb) = s;
        }
#pragma unroll
        for (int j = 0; j < 4; ++j) {
            const float4* ap = (const float4*)(lora_A + (size_t)(kb + j) * RANK);
            const float4 a0 = ap[0], a1 = ap[1], a2 = ap[2], a3 = ap[3];
            const float av[16] = {a0.x, a0.y, a0.z, a0.w, a1.x, a1.y, a1.z, a1.w,
                                  a2.x, a2.y, a2.z, a2.w, a3.x, a3.y, a3.z, a3.w};
#pragma unroll
            for (int a = 0; a < 4; ++a) {
                const float xs = (j == 0) ? xv[a].x : (j == 1) ? xv[a].y
                                : (j == 2) ? xv[a].z : xv[a].w;
#pragma unroll
                for (int r = 0; r < 16; ++r) p[a][r] += xs * av[r];
            }
        }
    }

#pragma unroll
    for (int a = 0; a < 4; ++a) {
#pragma unroll
        for (int r = 0; r < 16; ++r) {
            float v = p[a][r];
#pragma unroll
            for (int off = 32; off > 0; off >>= 1) v += __shfl_xor(v, off, 64);
            if (l == r)
                xe[(size_t)(t0 + a) * KE + DIN + r] = f2bf(4.0f * v);  // SCALING=4
        }
        if (l >= 16)  // cols 4112..4159: bias-one then zeros
            xe[(size_t)(t0 + a) * KE + DIN + l] =
                (l == 16) ? (unsigned short)0x3F80u : (unsigned short)0u;
    }
}

// ---------------------------------------------------------------------------
// Kernel 2: NF4 dequant W -> bf16 into [DOUT][KE], cols [0,4096).
// ---------------------------------------------------------------------------
__global__ __launch_bounds__(256) void dequant_w(const int* __restrict__ codes,
                                                 const float* __restrict__ absmax,
                                                 unsigned short* __restrict__ we) {
    __shared__ float tab[16];
    if (threadIdx.x < 16) tab[threadIdx.x] = NF4_CODE_D[threadIdx.x];
    __syncthreads();
    const size_t tid = (size_t)blockIdx.x * 256 + threadIdx.x;
    const size_t base = tid * 8;
    const int o = (int)(base >> 12);          // / DIN
    const int k = (int)(base & (DIN - 1));
    const float am = absmax[base >> 6];
    const int4 c0 = *(const int4*)(codes + base);
    const int4 c1 = *(const int4*)(codes + base + 4);
    u16x8 ov;
    ov[0] = f2bf(tab[c0.x] * am);
    ov[1] = f2bf(tab[c0.y] * am);
    ov[2] = f2bf(tab[c0.z] * am);
    ov[3] = f2bf(tab[c0.w] * am);
    ov[4] = f2bf(tab[c1.x] * am);
    ov[5] = f2bf(tab[c1.y] * am);
    ov[6] = f2bf(tab[c1.z] * am);
    ov[7] = f2bf(tab[c1.w] * am);
    *(u16x8*)(we + (size_t)o * KE + k) = ov;
}

// ---------------------------------------------------------------------------
// Kernel 3: W extended tail: cols [4096,4112) = lora_B^T, 4112 = bias, rest 0.
// ---------------------------------------------------------------------------
__global__ __launch_bounds__(256) void fill_wtail(const float* __restrict__ lora_B,
                                                  const float* __restrict__ bias,
                                                  unsigned short* __restrict__ we) {
    const int o = blockIdx.x * 256 + threadIdx.x;
    if (o >= DOUT) return;
    unsigned short* dst = we + (size_t)o * KE + DIN;
#pragma unroll
    for (int r = 0; r < RANK; ++r) dst[r] = f2bf(lora_B[(size_t)r * DOUT + o]);
    dst[16] = f2bf(bias[o]);
#pragma unroll
    for (int r = 17; r < 64; ++r) dst[r] = 0;
}

// ---------------------------------------------------------------------------
// Kernel 4: C[t,o] = sum_k A[t,k]*B[o,k]  (K-major bf16, K=KE)
// R3: 4-phase / K64-tile schedule (T3+T4+T5 on top of R2's swizzle+ledger).
// LDS: 4 k-slice slots (A[256][32] 16K + B[256][32] 16K = 32K each) = 128 KiB.
// slice (t,kh) -> slot (2t+kh)&3. Phase p stages one slice-half (2 loads) for
// tile t+1 and computes quadrant (kh, mh) = 16 MFMA.
// vmcnt ledger (per wave, 2 loads/phase): ph0 outstanding 8 -> vmcnt(4)
// retires (t,k0) A+B; ph2 outstanding 8 -> vmcnt(4) retires (t,k1); the wait
// precedes a barrier so all waves' loads are published before any ds_read.
// Last tile: ph2 uses vmcnt(0) (nothing staged this tile). Stage slots
// (2t+2/3)&3 are disjoint from read slots (2t/2t+1)&3.
// ---------------------------------------------------------------------------
__global__ __launch_bounds__(512, 2) void gemm_bt(const unsigned short* __restrict__ A,
                                                  const unsigned short* __restrict__ B,
                                                  float* __restrict__ C) {
    __shared__ __attribute__((aligned(1024))) char smem[4 * 32768];  // 128 KiB

    const int tid = threadIdx.x;
    const int l = tid & 63;
    const int w = tid >> 6;
    const int wm = w >> 2;      // 0..1
    const int wn = w & 3;       // 0..3

    const int tm = blockIdx.x >> 4;     // 32 row tiles
    const int tn = blockIdx.x & 15;     // 16 col tiles
    const int rowBase = tm * BM;
    const int colBase = tn * BN;

    // staging coords (pre-swizzled global source; linear LDS dest)
    int srow[2], scolb[2], loffs[2];
#pragma unroll
    for (int g = 0; g < 2; ++g) {
        const int loff = g * 8192 + tid * 16;               // linear LDS byte
        const int soff = loff ^ (((loff >> 7) & 7) << 4);   // involution
        loffs[g] = loff;
        srow[g] = soff >> 6;          // row of [256][32] bf16 slice
        scolb[g] = soff & 63;         // byte within 64B row
    }

    auto stageA = [&](int tt, int kh, int slot) {
        char* dst = smem + slot * 32768;
        const int k0 = tt * 64 + kh * 32;
#pragma unroll
        for (int g = 0; g < 2; ++g)
            async_copy16((const char*)A + ((size_t)(rowBase + srow[g]) * KE + k0) * 2 + scolb[g],
                         dst + loffs[g]);
    };
    auto stageB = [&](int tt, int kh, int slot) {
        char* dst = smem + slot * 32768 + 16384;
        const int k0 = tt * 64 + kh * 32;
#pragma unroll
        for (int g = 0; g < 2; ++g)
            async_copy16((const char*)B + ((size_t)(colBase + srow[g]) * KE + k0) * 2 + scolb[g],
                         dst + loffs[g]);
    };

    // swizzled fragment read offsets (within a 16 KiB slice)
    const int lmask = ((l >> 1) & 7) << 4;
    const int aoff = (((wm * 128 + (l & 15)) * 64) + ((l >> 4) * 16)) ^ lmask;
    const int boff = (((wn * 64 + (l & 15)) * 64) + ((l >> 4) * 16)) ^ lmask;

    f32x4 acc[8][4];
#pragma unroll
    for (int m = 0; m < 8; ++m)
#pragma unroll
        for (int n = 0; n < 4; ++n) acc[m][n] = (f32x4){0.f, 0.f, 0.f, 0.f};

    // prologue: tile 0 into slots 0,1 (order A0,B0,A1,B1 = ledger order)
    stageA(0, 0, 0); stageB(0, 0, 0);
    stageA(0, 1, 1); stageB(0, 1, 1);

    for (int t = 0; t < NKT64; ++t) {
        const char* S0 = smem + ((2 * t) & 3) * 32768;       // slice (t,k0)
        const char* S1 = smem + ((2 * t + 1) & 3) * 32768;   // slice (t,k1)
        const int d0 = (2 * t + 2) & 3, d1 = (2 * t + 3) & 3;
        const bool more = (t + 1 < NKT64);

        bf16x8 bf[4], af[4];

        // ---- phase 0: quadrant (k0, m 0..3) ----
        asm volatile("s_waitcnt vmcnt(4)" ::: "memory");
        __builtin_amdgcn_s_barrier();
        __builtin_amdgcn_sched_barrier(0);
        if (more) stageA(t + 1, 0, d0);
#pragma unroll
        for (int n = 0; n < 4; ++n)
            bf[n] = *(const bf16x8*)(S0 + 16384 + boff + n * 1024);
#pragma unroll
        for (int m = 0; m < 4; ++m)
            af[m] = *(const bf16x8*)(S0 + aoff + m * 1024);
        asm volatile("s_waitcnt lgkmcnt(0)" ::: "memory");
        __builtin_amdgcn_sched_barrier(0);
        __builtin_amdgcn_s_setprio(1);
#pragma unroll
        for (int m = 0; m < 4; ++m)
#pragma unroll
            for (int n = 0; n < 4; ++n)
                acc[m][n] = __builtin_amdgcn_mfma_f32_16x16x32_bf16(
                    af[m], bf[n], acc[m][n], 0, 0, 0);
        __builtin_amdgcn_s_setprio(0);
        __builtin_amdgcn_s_barrier();

        // ---- phase 1: quadrant (k0, m 4..7) ----
        if (more) stageB(t + 1, 0, d0);
#pragma unroll
        for (int m = 0; m < 4; ++m)
            af[m] = *(const bf16x8*)(S0 + aoff + (4 + m) * 1024);
        asm volatile("s_waitcnt lgkmcnt(0)" ::: "memory");
        __builtin_amdgcn_sched_barrier(0);
        __builtin_amdgcn_s_setprio(1);
#pragma unroll
        for (int m = 0; m < 4; ++m)
#pragma unroll
            for (int n = 0; n < 4; ++n)
                acc[4 + m][n] = __builtin_amdgcn_mfma_f32_16x16x32_bf16(
                    af[m], bf[n], acc[4 + m][n], 0, 0, 0);
        __builtin_amdgcn_s_setprio(0);

        // ---- phase 2: quadrant (k1, m 0..3) ----
        if (more) {
            asm volatile("s_waitcnt vmcnt(4)" ::: "memory");
        } else {
            asm volatile("s_waitcnt vmcnt(0)" ::: "memory");
        }
        __builtin_amdgcn_s_barrier();
        __builtin_amdgcn_sched_barrier(0);
        if (more) stageA(t + 1, 1, d1);
#pragma unroll
        for (int n = 0; n < 4; ++n)
            bf[n] = *(const bf16x8*)(S1 + 16384 + boff + n * 1024);
#pragma unroll
        for (int m = 0; m < 4; ++m)
            af[m] = *(const bf16x8*)(S1 + aoff + m * 1024);
        asm volatile("s_waitcnt lgkmcnt(0)" ::: "memory");
        __builtin_amdgcn_sched_barrier(0);
        __builtin_amdgcn_s_setprio(1);
#pragma unroll
        for (int m = 0; m < 4; ++m)
#pragma unroll
            for (int n = 0; n < 4; ++n)
                acc[m][n] = __builtin_amdgcn_mfma_f32_16x16x32_bf16(
                    af[m], bf[n], acc[m][n], 0, 0, 0);
        __builtin_amdgcn_s_setprio(0);
        __builtin_amdgcn_s_barrier();

        // ---- phase 3: quadrant (k1, m 4..7) ----
        if (more) stageB(t + 1, 1, d1);
#pragma unroll
        for (int m = 0; m < 4; ++m)
            af[m] = *(const bf16x8*)(S1 + aoff + (4 + m) * 1024);
        asm volatile("s_waitcnt lgkmcnt(0)" ::: "memory");
        __builtin_amdgcn_sched_barrier(0);
        __builtin_amdgcn_s_setprio(1);
#pragma unroll
        for (int m = 0; m < 4; ++m)
#pragma unroll
            for (int n = 0; n < 4; ++n)
                acc[4 + m][n] = __builtin_amdgcn_mfma_f32_16x16x32_bf16(
                    af[m], bf[n], acc[4 + m][n], 0, 0, 0);
        __builtin_amdgcn_s_setprio(0);
        // no trailing barrier: next tile's ph0 leads with vmcnt+barrier
    }

    // epilogue: C/D map col = l&15, row = (l>>4)*4 + reg
#pragma unroll
    for (int m = 0; m < 8; ++m) {
        const int rowg = rowBase + wm * 128 + m * 16 + (l >> 4) * 4;
#pragma unroll
        for (int n = 0; n < 4; ++n) {
            const int colg = colBase + wn * 64 + n * 16 + (l & 15);
            float* cp = C + (size_t)rowg * DOUT + colg;
#pragma unroll
            for (int r = 0; r < 4; ++r) cp[(size_t)r * DOUT] = acc[m][n][r];
        }
    }
}

// ---------------------------------------------------------------------------
extern "C" void kernel_launch(void* const* d_in, const int* in_sizes, int n_in,
                              void* d_out, int out_size, void* d_ws, size_t ws_size,
                              hipStream_t stream) {
    const float* x      = (const float*)d_in[0];
    const int*   codes  = (const int*)d_in[1];
    const float* absmax = (const float*)d_in[2];
    const float* bias   = (const float*)d_in[3];
    const float* lora_A = (const float*)d_in[4];
    const float* lora_B = (const float*)d_in[5];
    float* out = (float*)d_out;

    unsigned short* xe = (unsigned short*)d_ws;        // [TOK][KE] bf16
    unsigned short* we = xe + (size_t)TOK * KE;        // [DOUT][KE] bf16

    prep_x<<<TOK / 16, 256, 0, stream>>>(x, lora_A, xe);
    dequant_w<<<(DOUT * (size_t)DIN / 8) / 256, 256, 0, stream>>>(codes, absmax, we);
    fill_wtail<<<DOUT / 256, 256, 0, stream>>>(lora_B, bias, we);
    gemm_bt<<<(TOK / BM) * (DOUT / BN), 512, 0, stream>>>(xe, we, out);
}

// Round 4
// 362.363 us; speedup vs baseline: 1.4974x; 1.0214x over previous
//
#include <hip/hip_runtime.h>
#include <hip/hip_bf16.h>
#include <cstdint>
#include <cstddef>

#define TOK   8192
#define DIN   4096
#define DOUT  4096
#define RANK  16
#define KE    4160   // DIN + 16 (loraB) + 1 (bias) + 47 pad -> 65 * 64
#define NKT64 (KE / 64)

#define BM 256
#define BN 256

typedef __attribute__((ext_vector_type(8))) short bf16x8;
typedef __attribute__((ext_vector_type(4))) float f32x4;
typedef __attribute__((ext_vector_type(8))) unsigned short u16x8;

__device__ __constant__ float NF4_CODE_D[16] = {
    -1.0f, -0.6961928009986877f, -0.5250730514526367f, -0.39491748809814453f,
    -0.28444138169288635f, -0.18477343022823334f, -0.09105003625154495f, 0.0f,
    0.07958029955625534f, 0.16093020141124725f, 0.24611230194568634f,
    0.33791524171829224f, 0.44070982933044434f, 0.5626170039176941f,
    0.7229568362236023f, 1.0f};

__device__ __forceinline__ unsigned short f2bf(float f) {
    union { float f; unsigned u; } v; v.f = f;
    unsigned u = v.u;
    unsigned r = (u + 0x7FFFu + ((u >> 16) & 1u)) >> 16;  // round-nearest-even
    return (unsigned short)r;
}

__device__ __forceinline__ void async_copy16(const void* g, void* l) {
    __builtin_amdgcn_global_load_lds(
        (const __attribute__((address_space(1))) void*)g,
        (__attribute__((address_space(3))) void*)l,
        16, 0, 0);
}

// ---------------------------------------------------------------------------
// Kernel 1: x -> bf16 into [TOK][KE]; cols [4096,4112) = 4*(x@lora_A);
// col 4112 = 1.0 (bias col); [4113,4160) = 0.
// ---------------------------------------------------------------------------
__global__ __launch_bounds__(256) void prep_x(const float* __restrict__ x,
                                              const float* __restrict__ lora_A,
                                              unsigned short* __restrict__ xe) {
    const int tid = threadIdx.x;
    const int l = tid & 63;
    const int w = tid >> 6;
    const int t0 = blockIdx.x * 16 + w * 4;

    float p[4][16];
#pragma unroll
    for (int a = 0; a < 4; ++a)
#pragma unroll
        for (int r = 0; r < 16; ++r) p[a][r] = 0.f;

    for (int it = 0; it < 16; ++it) {
        const int kb = it * 256 + l * 4;
        float4 xv[4];
#pragma unroll
        for (int a = 0; a < 4; ++a)
            xv[a] = *(const float4*)(x + (size_t)(t0 + a) * DIN + kb);
#pragma unroll
        for (int a = 0; a < 4; ++a) {
            ushort4 s;
            s.x = f2bf(xv[a].x); s.y = f2bf(xv[a].y);
            s.z = f2bf(xv[a].z); s.w = f2bf(xv[a].w);
            *(ushort4*)(xe + (size_t)(t0 + a) * KE + kb) = s;
        }
#pragma unroll
        for (int j = 0; j < 4; ++j) {
            const float4* ap = (const float4*)(lora_A + (size_t)(kb + j) * RANK);
            const float4 a0 = ap[0], a1 = ap[1], a2 = ap[2], a3 = ap[3];
            const float av[16] = {a0.x, a0.y, a0.z, a0.w, a1.x, a1.y, a1.z, a1.w,
                                  a2.x, a2.y, a2.z, a2.w, a3.x, a3.y, a3.z, a3.w};
#pragma unroll
            for (int a = 0; a < 4; ++a) {
                const float xs = (j == 0) ? xv[a].x : (j == 1) ? xv[a].y
                                : (j == 2) ? xv[a].z : xv[a].w;
#pragma unroll
                for (int r = 0; r < 16; ++r) p[a][r] += xs * av[r];
            }
        }
    }

#pragma unroll
    for (int a = 0; a < 4; ++a) {
#pragma unroll
        for (int r = 0; r < 16; ++r) {
            float v = p[a][r];
#pragma unroll
            for (int off = 32; off > 0; off >>= 1) v += __shfl_xor(v, off, 64);
            if (l == r)
                xe[(size_t)(t0 + a) * KE + DIN + r] = f2bf(4.0f * v);  // SCALING=4
        }
        if (l >= 16)  // cols 4112..4159: bias-one then zeros
            xe[(size_t)(t0 + a) * KE + DIN + l] =
                (l == 16) ? (unsigned short)0x3F80u : (unsigned short)0u;
    }
}

// ---------------------------------------------------------------------------
// Kernel 2: NF4 dequant W -> bf16 into [DOUT][KE], cols [0,4096).
// ---------------------------------------------------------------------------
__global__ __launch_bounds__(256) void dequant_w(const int* __restrict__ codes,
                                                 const float* __restrict__ absmax,
                                                 unsigned short* __restrict__ we) {
    __shared__ float tab[16];
    if (threadIdx.x < 16) tab[threadIdx.x] = NF4_CODE_D[threadIdx.x];
    __syncthreads();
    const size_t tid = (size_t)blockIdx.x * 256 + threadIdx.x;
    const size_t base = tid * 8;
    const int o = (int)(base >> 12);          // / DIN
    const int k = (int)(base & (DIN - 1));
    const float am = absmax[base >> 6];
    const int4 c0 = *(const int4*)(codes + base);
    const int4 c1 = *(const int4*)(codes + base + 4);
    u16x8 ov;
    ov[0] = f2bf(tab[c0.x] * am);
    ov[1] = f2bf(tab[c0.y] * am);
    ov[2] = f2bf(tab[c0.z] * am);
    ov[3] = f2bf(tab[c0.w] * am);
    ov[4] = f2bf(tab[c1.x] * am);
    ov[5] = f2bf(tab[c1.y] * am);
    ov[6] = f2bf(tab[c1.z] * am);
    ov[7] = f2bf(tab[c1.w] * am);
    *(u16x8*)(we + (size_t)o * KE + k) = ov;
}

// ---------------------------------------------------------------------------
// Kernel 3: W extended tail: cols [4096,4112) = lora_B^T, 4112 = bias, rest 0.
// ---------------------------------------------------------------------------
__global__ __launch_bounds__(256) void fill_wtail(const float* __restrict__ lora_B,
                                                  const float* __restrict__ bias,
                                                  unsigned short* __restrict__ we) {
    const int o = blockIdx.x * 256 + threadIdx.x;
    if (o >= DOUT) return;
    unsigned short* dst = we + (size_t)o * KE + DIN;
#pragma unroll
    for (int r = 0; r < RANK; ++r) dst[r] = f2bf(lora_B[(size_t)r * DOUT + o]);
    dst[16] = f2bf(bias[o]);
#pragma unroll
    for (int r = 17; r < 64; ++r) dst[r] = 0;
}

// ---------------------------------------------------------------------------
// Kernel 4: C[t,o] = sum_k A[t,k]*B[o,k]  (K-major bf16, K=KE)
// R4: one-phase-ahead ds_read pipelining. 4 phases / K64-tile; phase p issues
// the ds_reads for phase p+1, then runs phase p's MFMA behind a
// compiler-counted lgkm wait (DS retires in order; newer = this phase's 4/8
// reads -> lgkmcnt(4)/(8) inserted automatically). NO explicit lgkmcnt(0).
// 2 barriers + 2 counted vmcnt per tile, at the slice-publication points.
//
// vmcnt ledger (per wave; 2 loads per stageA/stageB):
//   ph1-top: outstanding {A(t,1),B(t,1),A(t+1,0)}=6 -> vmcnt(2) retires S1(t)
//            (last tile: {A(L,1),B(L,1)}=4 -> vmcnt(0))
//   ph3-top: outstanding {A(t+1,0),B(t+1,0),A(t+1,1)}=6 -> vmcnt(2) retires
//            S0(t+1)
// WAR on slot reuse (slice s -> slot s&3, slots reused every 2 tiles): all
// reads of the old slice retire before their consuming MFMA's counted lgkm
// wait, which precedes the next ph1/ph3 barrier crossed by every wave before
// any wave issues the overwriting stage (stages always follow a barrier that
// postdates those waits). Publication: reads of newly staged slices occur
// only after the matching vmcnt+barrier (ph1: S1(t); ph3: S0(t+1); prologue:
// S0(0)).
// ---------------------------------------------------------------------------
__global__ __launch_bounds__(512, 2) void gemm_bt(const unsigned short* __restrict__ A,
                                                  const unsigned short* __restrict__ B,
                                                  float* __restrict__ C) {
    __shared__ __attribute__((aligned(1024))) char smem[4 * 32768];  // 128 KiB

    const int tid = threadIdx.x;
    const int l = tid & 63;
    const int w = tid >> 6;
    const int wm = w >> 2;      // 0..1
    const int wn = w & 3;       // 0..3

    const int tm = blockIdx.x >> 4;     // 32 row tiles
    const int tn = blockIdx.x & 15;     // 16 col tiles
    const int rowBase = tm * BM;
    const int colBase = tn * BN;

    // staging coords (pre-swizzled global source; linear LDS dest)
    int srow[2], scolb[2], loffs[2];
#pragma unroll
    for (int g = 0; g < 2; ++g) {
        const int loff = g * 8192 + tid * 16;               // linear LDS byte
        const int soff = loff ^ (((loff >> 7) & 7) << 4);   // involution
        loffs[g] = loff;
        srow[g] = soff >> 6;          // row of [256][32] bf16 slice
        scolb[g] = soff & 63;         // byte within 64B row
    }

    auto stageA = [&](int tt, int kh, int slot) {
        char* dst = smem + slot * 32768;
        const int k0 = tt * 64 + kh * 32;
#pragma unroll
        for (int g = 0; g < 2; ++g)
            async_copy16((const char*)A + ((size_t)(rowBase + srow[g]) * KE + k0) * 2 + scolb[g],
                         dst + loffs[g]);
    };
    auto stageB = [&](int tt, int kh, int slot) {
        char* dst = smem + slot * 32768 + 16384;
        const int k0 = tt * 64 + kh * 32;
#pragma unroll
        for (int g = 0; g < 2; ++g)
            async_copy16((const char*)B + ((size_t)(colBase + srow[g]) * KE + k0) * 2 + scolb[g],
                         dst + loffs[g]);
    };

    // swizzled fragment read offsets (within a 16 KiB slice)
    const int lmask = ((l >> 1) & 7) << 4;
    const int aoff = (((wm * 128 + (l & 15)) * 64) + ((l >> 4) * 16)) ^ lmask;
    const int boff = (((wn * 64 + (l & 15)) * 64) + ((l >> 4) * 16)) ^ lmask;

    f32x4 acc[8][4];
#pragma unroll
    for (int m = 0; m < 8; ++m)
#pragma unroll
        for (int n = 0; n < 4; ++n) acc[m][n] = (f32x4){0.f, 0.f, 0.f, 0.f};

    bf16x8 aLo[4], aHi[4], aLo2[4], aHi2[4], bCur[4], bNxt[4];

    // prologue: tile 0 slices into slots 0,1; publish S0(0); preload ph0 regs
    stageA(0, 0, 0); stageB(0, 0, 0);
    stageA(0, 1, 1); stageB(0, 1, 1);
    asm volatile("s_waitcnt vmcnt(4)" ::: "memory");
    __builtin_amdgcn_s_barrier();
    {
        const char* S0 = smem;  // slot 0
#pragma unroll
        for (int n = 0; n < 4; ++n)
            bCur[n] = *(const bf16x8*)(S0 + 16384 + boff + n * 1024);
#pragma unroll
        for (int m = 0; m < 4; ++m)
            aLo[m] = *(const bf16x8*)(S0 + aoff + m * 1024);
    }

    for (int t = 0; t < NKT64; ++t) {
        const char* S0 = smem + ((2 * t) & 3) * 32768;       // slice (t,k0)
        const char* S1 = smem + ((2 * t + 1) & 3) * 32768;   // slice (t,k1)
        const char* Sn = smem + ((2 * t + 2) & 3) * 32768;   // slice (t+1,k0)
        const int d0 = (2 * t + 2) & 3, d1 = (2 * t + 3) & 3;
        const bool more = (t + 1 < NKT64);

        // ---- phase 0: MFMA(aLo x bCur); prefetch-read aHi(S0) ----
#pragma unroll
        for (int m = 0; m < 4; ++m)
            aHi[m] = *(const bf16x8*)(S0 + aoff + (4 + m) * 1024);
        if (more) stageA(t + 1, 0, d0);
        __builtin_amdgcn_sched_barrier(0);
        __builtin_amdgcn_s_setprio(1);
#pragma unroll
        for (int m = 0; m < 4; ++m)
#pragma unroll
            for (int n = 0; n < 4; ++n)
                acc[m][n] = __builtin_amdgcn_mfma_f32_16x16x32_bf16(
                    aLo[m], bCur[n], acc[m][n], 0, 0, 0);
        __builtin_amdgcn_s_setprio(0);
        __builtin_amdgcn_sched_barrier(0);

        // ---- phase 1: publish S1(t); MFMA(aHi x bCur); read bNxt,aLo2(S1) --
        if (more) {
            asm volatile("s_waitcnt vmcnt(2)" ::: "memory");
        } else {
            asm volatile("s_waitcnt vmcnt(0)" ::: "memory");
        }
        __builtin_amdgcn_s_barrier();
        __builtin_amdgcn_sched_barrier(0);
#pragma unroll
        for (int n = 0; n < 4; ++n)
            bNxt[n] = *(const bf16x8*)(S1 + 16384 + boff + n * 1024);
#pragma unroll
        for (int m = 0; m < 4; ++m)
            aLo2[m] = *(const bf16x8*)(S1 + aoff + m * 1024);
        if (more) stageB(t + 1, 0, d0);
        __builtin_amdgcn_sched_barrier(0);
        __builtin_amdgcn_s_setprio(1);
#pragma unroll
        for (int m = 0; m < 4; ++m)
#pragma unroll
            for (int n = 0; n < 4; ++n)
                acc[4 + m][n] = __builtin_amdgcn_mfma_f32_16x16x32_bf16(
                    aHi[m], bCur[n], acc[4 + m][n], 0, 0, 0);
        __builtin_amdgcn_s_setprio(0);
        __builtin_amdgcn_sched_barrier(0);

        // ---- phase 2: MFMA(aLo2 x bNxt); prefetch-read aHi2(S1) ----
#pragma unroll
        for (int m = 0; m < 4; ++m)
            aHi2[m] = *(const bf16x8*)(S1 + aoff + (4 + m) * 1024);
        if (more) stageA(t + 1, 1, d1);
        __builtin_amdgcn_sched_barrier(0);
        __builtin_amdgcn_s_setprio(1);
#pragma unroll
        for (int m = 0; m < 4; ++m)
#pragma unroll
            for (int n = 0; n < 4; ++n)
                acc[m][n] = __builtin_amdgcn_mfma_f32_16x16x32_bf16(
                    aLo2[m], bNxt[n], acc[m][n], 0, 0, 0);
        __builtin_amdgcn_s_setprio(0);
        __builtin_amdgcn_sched_barrier(0);

        // ---- phase 3: publish S0(t+1); MFMA(aHi2 x bNxt); read bCur,aLo ----
        if (more) {
            asm volatile("s_waitcnt vmcnt(2)" ::: "memory");
            __builtin_amdgcn_s_barrier();
            __builtin_amdgcn_sched_barrier(0);
#pragma unroll
            for (int n = 0; n < 4; ++n)
                bCur[n] = *(const bf16x8*)(Sn + 16384 + boff + n * 1024);
#pragma unroll
            for (int m = 0; m < 4; ++m)
                aLo[m] = *(const bf16x8*)(Sn + aoff + m * 1024);
            stageB(t + 1, 1, d1);
        }
        __builtin_amdgcn_sched_barrier(0);
        __builtin_amdgcn_s_setprio(1);
#pragma unroll
        for (int m = 0; m < 4; ++m)
#pragma unroll
            for (int n = 0; n < 4; ++n)
                acc[4 + m][n] = __builtin_amdgcn_mfma_f32_16x16x32_bf16(
                    aHi2[m], bNxt[n], acc[4 + m][n], 0, 0, 0);
        __builtin_amdgcn_s_setprio(0);
        __builtin_amdgcn_sched_barrier(0);
    }

    // epilogue: C/D map col = l&15, row = (l>>4)*4 + reg
#pragma unroll
    for (int m = 0; m < 8; ++m) {
        const int rowg = rowBase + wm * 128 + m * 16 + (l >> 4) * 4;
#pragma unroll
        for (int n = 0; n < 4; ++n) {
            const int colg = colBase + wn * 64 + n * 16 + (l & 15);
            float* cp = C + (size_t)rowg * DOUT + colg;
#pragma unroll
            for (int r = 0; r < 4; ++r) cp[(size_t)r * DOUT] = acc[m][n][r];
        }
    }
}

// ---------------------------------------------------------------------------
extern "C" void kernel_launch(void* const* d_in, const int* in_sizes, int n_in,
                              void* d_out, int out_size, void* d_ws, size_t ws_size,
                              hipStream_t stream) {
    const float* x      = (const float*)d_in[0];
    const int*   codes  = (const int*)d_in[1];
    const float* absmax = (const float*)d_in[2];
    const float* bias   = (const float*)d_in[3];
    const float* lora_A = (const float*)d_in[4];
    const float* lora_B = (const float*)d_in[5];
    float* out = (float*)d_out;

    unsigned short* xe = (unsigned short*)d_ws;        // [TOK][KE] bf16
    unsigned short* we = xe + (size_t)TOK * KE;        // [DOUT][KE] bf16

    prep_x<<<TOK / 16, 256, 0, stream>>>(x, lora_A, xe);
    dequant_w<<<(DOUT * (size_t)DIN / 8) / 256, 256, 0, stream>>>(codes, absmax, we);
    fill_wtail<<<DOUT / 256, 256, 0, stream>>>(lora_B, bias, we);
    gemm_bt<<<(TOK / BM) * (DOUT / BN), 512, 0, stream>>>(xe, we, out);
}